// Round 1
// 9518.011 us; speedup vs baseline: 1.3568x; 1.3568x over previous
//
#include <hip/hip_runtime.h>

typedef __attribute__((ext_vector_type(8))) short short8;
typedef __attribute__((ext_vector_type(4))) float f32x4;
typedef __attribute__((ext_vector_type(2))) unsigned long long u64x2;

constexpr int Bsz = 128;   // batch
constexpr int Tlen = 512;  // seq len
constexpr int Hd = 1024;   // hidden
constexpr int K1 = 2048;   // L1 ring K = [h1 | y0]

__device__ __forceinline__ unsigned short f2b(float f) {
  unsigned int u = __float_as_uint(f);
  u = (u + 0x7FFFu + ((u >> 16) & 1u)) >> 16;
  return (unsigned short)u;
}
__device__ __forceinline__ unsigned long long aload64(const unsigned long long* p) {
  return __hip_atomic_load(p, __ATOMIC_RELAXED, __HIP_MEMORY_SCOPE_AGENT);
}
__device__ __forceinline__ unsigned int aload32(const unsigned int* p) {
  return __hip_atomic_load(p, __ATOMIC_RELAXED, __HIP_MEMORY_SCOPE_AGENT);
}
__device__ __forceinline__ void astore32(unsigned int* p, unsigned int v) {
  __hip_atomic_store(p, v, __ATOMIC_RELAXED, __HIP_MEMORY_SCOPE_AGENT);
}

// One persistent layer-slice worker. Wave w owns contiguous K-slice
// [w*KW, (w+1)*KW); its weight fragments live in registers for all 512 steps.
template <int LAYER>
__device__ __forceinline__ void run_layer(
    const int* __restrict__ src, const float* __restrict__ P,
    const unsigned short* __restrict__ Wh, const unsigned short* __restrict__ Wx,
    const float* __restrict__ bhh, const float* __restrict__ bih,
    float* __restrict__ dout, unsigned short* __restrict__ Ab,
    unsigned short* __restrict__ A1,
    unsigned int* __restrict__ flags,
    f32x4 (*__restrict__ red)[3][4][64],
    const int R0, const int J0, const int w, const int lane)
{
  constexpr int KSZ = LAYER ? 2048 : 1024;  // ring K
  constexpr int KW = KSZ / 4;               // K per wave
  constexpr int NK = KW / 32;               // k-steps per wave (8 or 16)
  constexpr int PD = 6;                     // A-load pipeline depth

  const int lrow = lane >> 4;
  const int lcol = lane & 15;
  const int col = J0 + lcol;

  const float bhr = bhh[col], bhz = bhh[1024 + col], bhn = bhh[2048 + col];
  float gbr = 0.f, gbz = 0.f, gbn = 0.f;
  if (LAYER) { gbr = bih[col]; gbz = bih[1024 + col]; gbn = bih[2048 + col]; }

  // ---- register-resident weights: B-fragment = W[col][k..k+7], 16B each.
  short8 wB[3][NK];
  {
    const int kw0 = w * KW + lrow * 8;
#pragma unroll
    for (int ks = 0; ks < NK; ++ks) {
      const int k0 = kw0 + ks * 32;
      const unsigned short* ws;
      if (LAYER && k0 >= 1024) ws = Wx + (k0 - 1024);  // x-part -> W_ih1
      else                     ws = Wh + k0;           // h-part
#pragma unroll
      for (int g = 0; g < 3; ++g)
        wB[g][ks] = *(const short8*)(ws + (g * 1024 + col) * 1024);
    }
  }

  const int myrow0 = R0 + w * 16 + lrow * 4;  // epilogue rows of this wave (f == w)
  float hold[4] = {0.f, 0.f, 0.f, 0.f};       // fp32 h carried in registers

  for (int r = 0; r <= 512; ++r) {
    const bool active = LAYER ? (r >= 1) : (r < 512);
    if (active) {
      const bool first = LAYER ? (r == 1) : (r == 0);
      const int par = r & 1;
      const unsigned short* Acur = Ab + par * (Bsz * KSZ);
      unsigned short* Anext = Ab + (par ^ 1) * (Bsz * KSZ);
      // first step: h == 0 -> skip h-part GEMM (ring h-region is uninitialized)
      const bool skipG = first && (LAYER == 0 || w < 2);

      float gpr[4], gpz[4], gpn[4];
      int sv[4];
      if (LAYER == 0) {
#pragma unroll
        for (int i = 0; i < 4; ++i) sv[i] = src[(myrow0 + i) * Tlen + r];
      } else {
#pragma unroll
        for (int i = 0; i < 4; ++i) { gpr[i] = gbr; gpz[i] = gbz; gpn[i] = gbn; }
      }

      f32x4 ar[4], az[4], an[4];
#pragma unroll
      for (int f = 0; f < 4; ++f) {
        ar[f] = (f32x4){0.f, 0.f, 0.f, 0.f};
        az[f] = (f32x4){0.f, 0.f, 0.f, 0.f};
        an[f] = (f32x4){0.f, 0.f, 0.f, 0.f};
      }

      u64x2 abuf[PD][4];            // rotating A-fragment buffer (all static idx)
      const unsigned short* abase[4];
      if (!skipG) {
#pragma unroll
        for (int f = 0; f < 4; ++f)
          abase[f] = Acur + (R0 + f * 16 + lcol) * KSZ + w * KW + lrow * 8;
        // prologue: fill the pipe
#pragma unroll
        for (int ks = 0; ks < PD; ++ks) {
#pragma unroll
          for (int f = 0; f < 4; ++f) {
            const unsigned long long* ap =
                (const unsigned long long*)(abase[f] + ks * 32);
            abuf[ks][f][0] = aload64(ap);
            abuf[ks][f][1] = aload64(ap + 1);
          }
        }
      }
      if (LAYER == 0) {  // P gather issued after A-prologue; consumed at epilogue
#pragma unroll
        for (int i = 0; i < 4; ++i) {
          const float* pr = P + sv[i] * 3072 + col;
          gpr[i] = pr[0]; gpz[i] = pr[1024]; gpn[i] = pr[2048];
        }
      }
      if (!skipG) {
#pragma unroll
        for (int ks = 0; ks < NK; ++ks) {
#pragma unroll
          for (int f = 0; f < 4; ++f) {
            const short8 a = *(const short8*)&abuf[ks % PD][f];
            ar[f] = __builtin_amdgcn_mfma_f32_16x16x32_bf16(a, wB[0][ks], ar[f], 0, 0, 0);
            az[f] = __builtin_amdgcn_mfma_f32_16x16x32_bf16(a, wB[1][ks], az[f], 0, 0, 0);
            an[f] = __builtin_amdgcn_mfma_f32_16x16x32_bf16(a, wB[2][ks], an[f], 0, 0, 0);
          }
          if (ks + PD < NK) {  // refill the slot just consumed
#pragma unroll
            for (int f = 0; f < 4; ++f) {
              const unsigned long long* ap =
                  (const unsigned long long*)(abase[f] + (ks + PD) * 32);
              abuf[(ks + PD) % PD][f][0] = aload64(ap);
              abuf[(ks + PD) % PD][f][1] = aload64(ap + 1);
            }
          }
        }
      }

      // ---- cross-wave reduction: wave ww sends f != ww, keeps f == ww
#pragma unroll
      for (int f = 0; f < 4; ++f) {
        if (f != w) {
          red[w][0][f][lane] = ar[f];
          red[w][1][f][lane] = az[f];
          red[w][2][f][lane] = an[f];
        }
      }
      __syncthreads();
      f32x4 sr  = (f32x4){0.f, 0.f, 0.f, 0.f};
      f32x4 sz  = (f32x4){0.f, 0.f, 0.f, 0.f};
      f32x4 snh = (f32x4){0.f, 0.f, 0.f, 0.f};
      f32x4 snx = (f32x4){0.f, 0.f, 0.f, 0.f};
      const bool ownH = (LAYER == 0) || (w < 2);
#pragma unroll
      for (int f = 0; f < 4; ++f) {
        if (f == w) {
          sr = ar[f]; sz = az[f];
          if (ownH) snh = an[f]; else snx = an[f];
        }
      }
#pragma unroll
      for (int ww = 0; ww < 4; ++ww) {
        if (ww != w) {
          sr += red[ww][0][w][lane];
          sz += red[ww][1][w][lane];
          const f32x4 nn = red[ww][2][w][lane];
          if (LAYER == 0 || ww < 2) snh += nn; else snx += nn;
        }
      }

      // ---- 4-wave parallel epilogue (wave w owns rows myrow0..+3, col)
      const bool lastw = LAYER ? (r == 512) : (r == 511);
#pragma unroll
      for (int i = 0; i < 4; ++i) {
        const int row = myrow0 + i;
        float rg = sr[i] + gpr[i] + bhr;
        rg = 1.f / (1.f + __expf(-rg));
        float zg = sz[i] + gpz[i] + bhz;
        zg = 1.f / (1.f + __expf(-zg));
        const float nx = (snx[i] + gpn[i]) + rg * (snh[i] + bhn);
        const float e2 = __expf(2.f * fabsf(nx));
        const float ng = copysignf(1.f - 2.f / (e2 + 1.f), nx);
        const float hnew = (1.f - zg) * ng + zg * hold[i];
        hold[i] = hnew;
        const unsigned int hb = (unsigned int)f2b(hnew);
        const unsigned int nb = (unsigned int)__shfl_down((int)hb, 1, 64);
        if ((lcol & 1) == 0) {
          const unsigned int pv = hb | (nb << 16);
          astore32((unsigned int*)(Anext + row * KSZ + J0 + lcol), pv);
          if (LAYER == 0)
            astore32((unsigned int*)(A1 + (par ^ 1) * (Bsz * K1) +
                                     row * K1 + 1024 + J0 + lcol), pv);
        }
        if (lastw) dout[LAYER * (Bsz * Hd) + row * Hd + col] = hnew;
      }
    }

    // ---- grid barrier: per-block flag line + lane-parallel poll (unchanged)
    if (r < 512) {
      __syncthreads();   // all waves' ring stores drained (vmcnt0 before s_barrier)
      if (w == 0) {
        const unsigned tgt = (unsigned)(r + 1);
        if (lane == 0) astore32(&flags[(unsigned)blockIdx.x * 16u], tgt);
        for (;;) {
          const unsigned m0 = aload32(&flags[(unsigned)(lane)       * 16u]);
          const unsigned m1 = aload32(&flags[(unsigned)(lane + 64)  * 16u]);
          const unsigned m2 = aload32(&flags[(unsigned)(lane + 128) * 16u]);
          const unsigned m3 = aload32(&flags[(unsigned)(lane + 192) * 16u]);
          if (__all(m0 >= tgt && m1 >= tgt && m2 >= tgt && m3 >= tgt)) break;
          __builtin_amdgcn_s_sleep(2);
        }
      }
      __syncthreads();
    }
  }
}

__global__ void __launch_bounds__(256, 1) gru_persist(
    const int* __restrict__ src,
    const float* __restrict__ P,              // [512][3072] fp32 (incl. bih0)
    const unsigned short* __restrict__ Whh0b, // [3072][1024] bf16
    const unsigned short* __restrict__ Whh1b,
    const unsigned short* __restrict__ Wih1b,
    const float* __restrict__ bhh0,
    const float* __restrict__ bih1,
    const float* __restrict__ bhh1,
    float* __restrict__ dout,
    unsigned short* __restrict__ A0,
    unsigned short* __restrict__ A1,
    unsigned int* __restrict__ flags,
    int* __restrict__ taken)
{
  __shared__ f32x4 red[4][3][4][64];   // 48 KiB reduction buffer
  __shared__ int s_work;

  const int tid = threadIdx.x;

  // ---- XCD-affinity work claiming: per-XCD weight slice stays L2-resident.
  if (tid == 0) {
    unsigned int xcc;
    asm volatile("s_getreg_b32 %0, hwreg(HW_REG_XCC_ID)" : "=s"(xcc));
    const int pref = ((int)(xcc & 7u)) * 32;
    int got = -1;
    for (int j = 0; j < 256; ++j) {
      const int idx = (pref + j) & 255;
      int expected = 0;
      if (__hip_atomic_compare_exchange_strong(&taken[idx], &expected, 1,
              __ATOMIC_RELAXED, __ATOMIC_RELAXED, __HIP_MEMORY_SCOPE_AGENT)) {
        got = idx; break;
      }
    }
    s_work = got;
  }
  __syncthreads();
  const int work = s_work;
  const int xcd_w = work >> 5;          // 0..7
  const int slot = work & 31;
  const int layer = (slot >> 4) & 1;
  const int c = xcd_w * 8 + ((slot >> 1) & 7);   // gate-triple 0..63
  const int mh = slot & 1;
  const int R0 = mh * 64;
  const int J0 = c * 16;

  const int w = tid >> 6;
  const int lane = tid & 63;

  if (layer == 0)
    run_layer<0>(src, P, Whh0b, Wih1b, bhh0, bih1, dout, A0, A1, flags, red,
                 R0, J0, w, lane);
  else
    run_layer<1>(src, P, Whh1b, Wih1b, bhh1, bih1, dout, A1, A1, flags, red,
                 R0, J0, w, lane);
}

// ---------------- prep kernels ----------------
__global__ void __launch_bounds__(256) cvt_k(const float* __restrict__ s,
                                            unsigned short* __restrict__ d, int n) {
  const int i = (blockIdx.x * 256 + threadIdx.x) * 8;
  if (i >= n) return;
  const float4 a = *(const float4*)(s + i);
  const float4 b = *(const float4*)(s + i + 4);
  short8 o;
  o[0] = (short)f2b(a.x); o[1] = (short)f2b(a.y);
  o[2] = (short)f2b(a.z); o[3] = (short)f2b(a.w);
  o[4] = (short)f2b(b.x); o[5] = (short)f2b(b.y);
  o[6] = (short)f2b(b.z); o[7] = (short)f2b(b.w);
  *(short8*)(d + i) = o;
}

__global__ void __launch_bounds__(256) pemb_k(const float* __restrict__ emb,
                                             const float* __restrict__ wih0,
                                             const float* __restrict__ bih0,
                                             float* __restrict__ P) {
  __shared__ float se[64 * 64];
  const int g = blockIdx.x * 256 + threadIdx.x;
  const int v0 = blockIdx.y * 64;
  float acc[64];
#pragma unroll
  for (int i = 0; i < 64; ++i) acc[i] = 0.f;
  for (int kb = 0; kb < 8; ++kb) {
    __syncthreads();
#pragma unroll
    for (int s = 0; s < 4; ++s) {
      const int idx = threadIdx.x + s * 256;
      const int vv = idx >> 4, k4 = (idx & 15) * 4;
      *(float4*)(se + vv * 64 + k4) =
          *(const float4*)(emb + (v0 + vv) * 512 + kb * 64 + k4);
    }
    __syncthreads();
    float4 wv[16];
#pragma unroll
    for (int j = 0; j < 16; ++j)
      wv[j] = *(const float4*)(wih0 + g * 512 + kb * 64 + j * 4);
    for (int vv = 0; vv < 64; ++vv) {
      const float* er = se + vv * 64;
      float s0 = acc[vv];
#pragma unroll
      for (int j = 0; j < 16; ++j) {
        const float4 e = *(const float4*)(er + j * 4);
        s0 += wv[j].x * e.x + wv[j].y * e.y + wv[j].z * e.z + wv[j].w * e.w;
      }
      acc[vv] = s0;
    }
  }
  const float bb = bih0[g];
  for (int vv = 0; vv < 64; ++vv) P[(v0 + vv) * 3072 + g] = acc[vv] + bb;
}

__global__ void zero_k(unsigned int* flags, int* taken) {
  const int i = threadIdx.x;           // 0..255
  for (int j = 0; j < 16; ++j) flags[i * 16 + j] = 0u;
  taken[i] = 0;
}

extern "C" void kernel_launch(void* const* d_in, const int* in_sizes, int n_in,
                              void* d_out, int out_size, void* d_ws, size_t ws_size,
                              hipStream_t stream) {
  const int* src = (const int*)d_in[0];
  const float* emb = (const float*)d_in[1];
  const float* wih0 = (const float*)d_in[2];
  const float* whh0 = (const float*)d_in[3];
  const float* bih0 = (const float*)d_in[4];
  const float* bhh0 = (const float*)d_in[5];
  const float* wih1 = (const float*)d_in[6];
  const float* whh1 = (const float*)d_in[7];
  const float* bih1 = (const float*)d_in[8];
  const float* bhh1 = (const float*)d_in[9];
  float* dout = (float*)d_out;

  char* p = (char*)d_ws;
  unsigned short* A0 = (unsigned short*)p;                       // 524288 B
  unsigned short* A1 = (unsigned short*)(p + 524288);            // 1048576 B
  unsigned short* Whh0b = (unsigned short*)(p + 1572864);        // 6291456 B
  unsigned short* Whh1b = (unsigned short*)(p + 7864320);        // 6291456 B
  unsigned short* Wih1b = (unsigned short*)(p + 14155776);       // 6291456 B
  float* P = (float*)(p + 20447232);                             // 6291456 B
  unsigned int* flags = (unsigned int*)(p + 26738688);           // 16384 B
  int* taken = (int*)(p + 26755072);                             // 1024 B

  constexpr int NW = 3072 * 1024;
  hipLaunchKernelGGL(cvt_k, dim3(NW / (256 * 8)), dim3(256), 0, stream, whh0, Whh0b, NW);
  hipLaunchKernelGGL(cvt_k, dim3(NW / (256 * 8)), dim3(256), 0, stream, whh1, Whh1b, NW);
  hipLaunchKernelGGL(cvt_k, dim3(NW / (256 * 8)), dim3(256), 0, stream, wih1, Wih1b, NW);
  hipLaunchKernelGGL(pemb_k, dim3(12, 8), dim3(256), 0, stream, emb, wih0, bih0, P);
  hipLaunchKernelGGL(zero_k, dim3(1), dim3(256), 0, stream, flags, taken);

  hipLaunchKernelGGL(gru_persist, dim3(256), dim3(256), 0, stream,
                     src, P, Whh0b, Whh1b, Wih1b, bhh0, bih1, bhh1,
                     dout, A0, A1, flags, taken);
}